// Round 7
// baseline (87450.824 us; speedup 1.0000x reference)
//
#include <hip/hip_runtime.h>
#include <math.h>

#define NLFULL 504
#define REAL_NL 500
#define BATCH 2048
#define NZ 50
#define NC 21
#define GHID 512
#define EPSB 1e-5f
#define LO_SCALE 2048.0f
#define INV_LO (1.0f / 2048.0f)

typedef __attribute__((ext_vector_type(4))) float f32x4;
typedef __attribute__((ext_vector_type(8))) _Float16 half8;
typedef __attribute__((ext_vector_type(4))) unsigned uint4v;

__device__ __forceinline__ void split2(float x, _Float16& hi, _Float16& lo) {
    hi = (_Float16)x;
    lo = (_Float16)((x - (float)hi) * LO_SCALE);
}
__device__ __forceinline__ unsigned packh(float x) {
    _Float16 hi, lo; split2(x, hi, lo);
    return (unsigned)__builtin_bit_cast(unsigned short, hi)
         | ((unsigned)__builtin_bit_cast(unsigned short, lo) << 16);
}
__device__ __forceinline__ float unpackh(unsigned w) {
    _Float16 hi = __builtin_bit_cast(_Float16, (unsigned short)(w & 0xFFFFu));
    _Float16 lo = __builtin_bit_cast(_Float16, (unsigned short)(w >> 16));
    return (float)hi + (float)lo * INV_LO;
}

// coherent (LLC) load of 8 interleaved h elems -> hi/lo half8 frags
__device__ __forceinline__ void load_hfrag(const unsigned* H, size_t eoff,
                                           half8& aH, half8& aL) {
    unsigned long long* p = (unsigned long long*)(H + eoff);
    unsigned long long d0 = __hip_atomic_load(p + 0, __ATOMIC_RELAXED, __HIP_MEMORY_SCOPE_AGENT);
    unsigned long long d1 = __hip_atomic_load(p + 1, __ATOMIC_RELAXED, __HIP_MEMORY_SCOPE_AGENT);
    unsigned long long d2 = __hip_atomic_load(p + 2, __ATOMIC_RELAXED, __HIP_MEMORY_SCOPE_AGENT);
    unsigned long long d3 = __hip_atomic_load(p + 3, __ATOMIC_RELAXED, __HIP_MEMORY_SCOPE_AGENT);
    unsigned w0 = (unsigned)d0, w1 = (unsigned)(d0 >> 32);
    unsigned w2 = (unsigned)d1, w3 = (unsigned)(d1 >> 32);
    unsigned w4 = (unsigned)d2, w5 = (unsigned)(d2 >> 32);
    unsigned w6 = (unsigned)d3, w7 = (unsigned)(d3 >> 32);
    uint4v hw, lw;
    hw.x = (w0 & 0xFFFFu) | (w1 << 16);
    hw.y = (w2 & 0xFFFFu) | (w3 << 16);
    hw.z = (w4 & 0xFFFFu) | (w5 << 16);
    hw.w = (w6 & 0xFFFFu) | (w7 << 16);
    lw.x = (w0 >> 16) | (w1 & 0xFFFF0000u);
    lw.y = (w2 >> 16) | (w3 & 0xFFFF0000u);
    lw.z = (w4 >> 16) | (w5 & 0xFFFF0000u);
    lw.w = (w6 >> 16) | (w7 & 0xFFFF0000u);
    aH = __builtin_bit_cast(half8, hw);
    aL = __builtin_bit_cast(half8, lw);
}

// =============================== upsample ==================================
__global__ __launch_bounds__(512) void upsample_kernel(
    const float* __restrict__ z, const float* __restrict__ dW, const float* __restrict__ db,
    const float* __restrict__ W0, const float* __restrict__ g0, const float* __restrict__ bb0,
    const float* __restrict__ m0, const float* __restrict__ v0, const float* __restrict__ al0,
    const float* __restrict__ W1, const float* __restrict__ g1, const float* __restrict__ bb1,
    const float* __restrict__ m1, const float* __restrict__ v1, const float* __restrict__ al1,
    const float* __restrict__ W2, const float* __restrict__ g2, const float* __restrict__ bb2,
    const float* __restrict__ m2, const float* __restrict__ v2, const float* __restrict__ al2,
    float* __restrict__ hseq)
{
    __shared__ float bufA[5712];
    __shared__ float bufB[5544];
    __shared__ float zl[52];

    const int b   = blockIdx.x;
    const int ta  = blockIdx.y * 16;
    const int nt0 = min(16, 63 - ta);
    const int tid = threadIdx.x;

    if (tid < NZ) zl[tid] = z[b * NZ + tid];
    __syncthreads();

    for (int i = tid; i < 336 * nt0; i += 512) {
        int c = i % 336, tt = i / 336;
        int row = c * 63 + ta + tt;
        const float* wr = dW + (size_t)row * NZ;
        float s = db[row];
        #pragma unroll
        for (int n = 0; n < NZ; ++n) s += zl[n] * wr[n];
        bufA[c * 17 + tt] = s;
    }
    __syncthreads();

    const float a0 = al0[0], a1 = al1[0], a2 = al2[0];

    for (int i = tid; i < 168 * 2 * nt0; i += 512) {
        int o = i % 168, tt1 = i / 168;
        int tt = tt1 >> 1, k = tt1 & 1;
        const float* wp = W0 + o * 2 + k;
        float s = 0.f;
        for (int c = 0; c < 336; ++c) s += bufA[c * 17 + tt] * wp[c * 336];
        float sc = g0[o] / sqrtf(v0[o] + EPSB);
        s = (s - m0[o]) * sc + bb0[o];
        s = (s >= 0.f) ? s : a0 * s;
        bufB[o * 33 + tt1] = s;
    }
    __syncthreads();

    for (int i = tid; i < 84 * 4 * nt0; i += 512) {
        int o = i % 84, tt2 = i / 84;
        int tt1 = tt2 >> 1, k = tt2 & 1;
        const float* wp = W1 + o * 2 + k;
        float s = 0.f;
        for (int c = 0; c < 168; ++c) s += bufB[c * 33 + tt1] * wp[c * 168];
        float sc = g1[o] / sqrtf(v1[o] + EPSB);
        s = (s - m1[o]) * sc + bb1[o];
        s = (s >= 0.f) ? s : a1 * s;
        bufA[o * 65 + tt2] = s;
    }
    __syncthreads();

    for (int i = tid; i < 42 * 8 * nt0; i += 512) {
        int o = i % 42, tt3 = i / 42;
        int tt2 = tt3 >> 1, k = tt3 & 1;
        const float* wp = W2 + o * 2 + k;
        float s = 0.f;
        for (int c = 0; c < 84; ++c) s += bufA[c * 65 + tt2] * wp[c * 84];
        float sc = g2[o] / sqrtf(v2[o] + EPSB);
        s = (s - m2[o]) * sc + bb2[o];
        s = (s >= 0.f) ? s : a2 * s;
        int t3 = 8 * ta + tt3;
        hseq[(size_t)t3 * (BATCH * 42) + b * 42 + o] = s;
    }
}

// ================= table: gi-contribution of one-hot px =====================
__global__ void table_kernel(const float* __restrict__ w_px, const float* __restrict__ b_px,
                             const float* __restrict__ w_ih, const float* __restrict__ b_ih,
                             float* __restrict__ table)
{
    int i = blockIdx.x * 256 + threadIdx.x;
    if (i >= 22 * 1536) return;
    int e = i / 1536, jg = i % 1536;
    const float* wih = w_ih + jg * 63 + 42;
    float s = b_ih[jg];
    #pragma unroll
    for (int jp = 0; jp < NC; ++jp) {
        float px = b_px[jp] + (e < NC ? w_px[jp * NC + e] : 0.f);
        s += px * wih[jp];
    }
    table[i] = s;
}

// ====== pack weights into MFMA B-fragment order, fp16 2-limb (lo x2048) =====
__global__ void pack_whh_kernel(const float* __restrict__ w_hh,
                                _Float16* __restrict__ pH, _Float16* __restrict__ pL)
{
    int i = blockIdx.x * 256 + threadIdx.x;
    if (i >= 3 * 32 * 16 * 512) return;
    int e = i & 7, l = (i >> 3) & 63, kf = (i >> 9) & 15, nf = (i >> 13) & 31, g = i >> 18;
    int n = nf * 16 + (l & 15);
    int k = kf * 32 + ((l >> 4) << 3) + e;
    float v = w_hh[(size_t)(g * GHID + n) * GHID + k];
    _Float16 hi, lo; split2(v, hi, lo);
    pH[i] = hi; pL[i] = lo;
}

__global__ void pack_wih_kernel(const float* __restrict__ w_ih,
                                _Float16* __restrict__ pH, _Float16* __restrict__ pL)
{
    int i = blockIdx.x * 256 + threadIdx.x;
    if (i >= 3 * 32 * 2 * 512) return;
    int e = i & 7, l = (i >> 3) & 63, kf = (i >> 9) & 1, nf = (i >> 10) & 31, g = i >> 15;
    int n = nf * 16 + (l & 15);
    int k = kf * 32 + ((l >> 4) << 3) + e;
    float v = (k < 42) ? w_ih[(size_t)(g * GHID + n) * 63 + k] : 0.f;
    _Float16 hi, lo; split2(v, hi, lo);
    pH[i] = hi; pL[i] = lo;
}

__global__ void pack_wout_kernel(const float* __restrict__ w_out,
                                 _Float16* __restrict__ pH, _Float16* __restrict__ pL)
{
    int i = blockIdx.x * 256 + threadIdx.x;
    if (i >= 2 * 16 * 512) return;
    int e = i & 7, l = (i >> 3) & 63, kf = (i >> 9) & 15, nf = i >> 13;
    int n = nf * 16 + (l & 15);
    int k = kf * 32 + ((l >> 4) << 3) + e;
    float v = (n < NC) ? w_out[(size_t)n * GHID + k] : 0.f;
    _Float16 hi, lo; split2(v, hi, lo);
    pH[i] = hi; pL[i] = lo;
}

// ============ init h0 (interleaved u32 = 0) and barrier counter =============
__global__ void init_kernel(unsigned* __restrict__ hA, int* __restrict__ bar)
{
    int i = blockIdx.x * 256 + threadIdx.x;
    if (i < BATCH * GHID) hA[i] = 0u;
    if (i < 64) bar[i] = 0;
}

// ==================== persistent 500-step decode ============================
// 256 blocks x 512 thr, 1 block/CU, cooperative. Block = 64 rows x 64 cols x
// 3 gates (32 m-tiles x 8 n-tiles; bid&7 = n-tile = XCD heuristic so the
// 470 KB read-only B-slice stays L2-resident all 500 steps). 8 waves =
// 4 mw x 2 nw; wave = 16 rows, 2 gate-nf, 1 logits-nf (full K).
// All mutable cross-block state (h) moves via agent-scope atomics (LLC =
// coherence point) -> placement-independent correctness (G16), no reliance
// on fence-invalidation of non-coherent per-XCD L2s (r6's failure).
// ONE global barrier per step: logits+argmax for the block's own rows are
// recomputed redundantly per block from the SAME A-frags the gates use
// (bit-identical across duplicates -> deterministic idx, no idx traffic).
#define MFMA3(mainA, crossA, aH_, aL_, bH_, bL_)                                   \
    mainA  = __builtin_amdgcn_mfma_f32_16x16x32_f16(aH_, bH_, mainA, 0, 0, 0);     \
    crossA = __builtin_amdgcn_mfma_f32_16x16x32_f16(aH_, bL_, crossA, 0, 0, 0);    \
    crossA = __builtin_amdgcn_mfma_f32_16x16x32_f16(aL_, bH_, crossA, 0, 0, 0);

struct GruP {
    unsigned *hA, *hB;                 // interleaved h ping-pong
    const float* hseq;
    const float* table;
    const _Float16 *whhH, *whhL, *wihH, *wihL, *woH, *woL;
    const float *b_hh, *b_out;
    float* out;
    int* bar;
};

__global__ __launch_bounds__(512, 1) void gru_persistent(GruP p)
{
    __shared__ float lgbuf[64][33];
    __shared__ int   idx_l[64];

    const int bid = blockIdx.x;        // 0..255
    const int nb  = bid & 7;           // n-tile (XCD heuristic)
    const int mb  = bid >> 3;          // m-tile 0..31
    const int m0  = mb * 64;
    const int tid = threadIdx.x;
    const int l   = tid & 63, wv = tid >> 6;
    const int mw  = wv >> 1, nw = wv & 1;
    const int lrow = l & 15, lk = (l >> 4) << 3;

    const int rowg = m0 + mw * 16 + lrow;       // this lane's A-frag row
    const size_t abase = (size_t)rowg * GHID;
    const int nf0 = nb * 4 + nw * 2;            // gates nf base (2 nf per wave)
    int epoch = 0;

    for (int i = 1; i <= REAL_NL + 1; ++i) {
        // ---------------- global barrier (release-add / relaxed-spin) --------
        __syncthreads();                        // drains this block's h stores
        ++epoch;
        if (tid == 0) {
            __hip_atomic_fetch_add(p.bar, 1, __ATOMIC_RELEASE, __HIP_MEMORY_SCOPE_AGENT);
            while (__hip_atomic_load(p.bar, __ATOMIC_RELAXED, __HIP_MEMORY_SCOPE_AGENT)
                   < epoch * 256)
                __builtin_amdgcn_s_sleep(1);
        }
        __syncthreads();

        const unsigned* Hp = (i & 1) ? p.hA : p.hB;   // H[i-1]
        unsigned*       Hn = (i & 1) ? p.hB : p.hA;   // H[i]
        const float*    ht = p.hseq + (size_t)(i - 1) * (BATCH * 42);
        const bool    do_g = (i <= REAL_NL);

        f32x4 gM[4][2], gX[4][2];      // gate streams: 0=r 1=z 2=in 3=hn
        f32x4 lM = (f32x4)0.f, lX = (f32x4)0.f;
        #pragma unroll
        for (int s = 0; s < 4; ++s)
            #pragma unroll
            for (int cc = 0; cc < 2; ++cc) { gM[s][cc] = (f32x4)0.f; gX[s][cc] = (f32x4)0.f; }

        // ---- H part: K = 512 = 16 k-frags (A via LLC-coherent loads) --------
        for (int kf = 0; kf < 16; ++kf) {
            half8 aH, aL;
            load_hfrag(Hp, abase + kf * 32 + lk, aH, aL);
            {   // logits (lnf = nw, full K)
                size_t bo = ((size_t)(nw * 16 + kf) << 9) + (l << 3);
                half8 bH = *(const half8*)(p.woH + bo);
                half8 bL = *(const half8*)(p.woL + bo);
                MFMA3(lM, lX, aH, aL, bH, bL);
            }
            if (do_g) {
                #pragma unroll
                for (int g = 0; g < 3; ++g) {
                    #pragma unroll
                    for (int cc = 0; cc < 2; ++cc) {
                        size_t bo = ((size_t)((g * 32 + nf0 + cc) * 16 + kf) << 9) + (l << 3);
                        half8 bH = *(const half8*)(p.whhH + bo);
                        half8 bL = *(const half8*)(p.whhL + bo);
                        const int s = (g == 2) ? 3 : g;
                        MFMA3(gM[s][cc], gX[s][cc], aH, aL, bH, bL);
                    }
                }
            }
        }

        // ---- I part: K = 42 (read-only hseq, on-the-fly split) --------------
        if (do_g) {
            #pragma unroll
            for (int kf = 0; kf < 2; ++kf) {
                half8 aH, aL;
                const float* rp = ht + (size_t)rowg * 42;
                #pragma unroll
                for (int e = 0; e < 8; ++e) {
                    int k = kf * 32 + lk + e;
                    float f = (k < 42) ? rp[k] : 0.f;
                    _Float16 hi, lo; split2(f, hi, lo);
                    aH[e] = hi; aL[e] = lo;
                }
                #pragma unroll
                for (int g = 0; g < 3; ++g) {
                    #pragma unroll
                    for (int cc = 0; cc < 2; ++cc) {
                        size_t bo = ((size_t)((g * 32 + nf0 + cc) * 2 + kf) << 9) + (l << 3);
                        half8 bH = *(const half8*)(p.wihH + bo);
                        half8 bL = *(const half8*)(p.wihL + bo);
                        const int s = (g == 2) ? 2 : g;
                        MFMA3(gM[s][cc], gX[s][cc], aH, aL, bH, bL);
                    }
                }
            }
        }

        // ---- logits -> LDS, argmax, out[i-2] --------------------------------
        {
            int col = nw * 16 + lrow;
            float bias = (col < NC) ? p.b_out[col] : 0.f;
            #pragma unroll
            for (int r = 0; r < 4; ++r) {
                int row = mw * 16 + ((l >> 4) << 2) + r;
                lgbuf[row][col] = lM[r] + lX[r] * INV_LO + bias;
            }
        }
        __syncthreads();
        if (tid < 64) {
            int bi = NC;                      // i==1: zeros-x1h table entry
            if (i > 1) {
                float best = lgbuf[tid][0]; bi = 0;
                #pragma unroll
                for (int c = 1; c < NC; ++c) {
                    float v = lgbuf[tid][c];
                    if (v > best) { best = v; bi = c; }   // strict > = first max
                }
                if (nb == 0) {
                    float* op = p.out + (size_t)(m0 + tid) * (REAL_NL * NC)
                                      + (size_t)(i - 2) * NC;
                    #pragma unroll
                    for (int c = 0; c < NC; ++c) op[c] = lgbuf[tid][c];
                }
            }
            idx_l[tid] = bi;
        }
        __syncthreads();

        // ---- epilogue: gate math + coherent h store -------------------------
        if (do_g) {
            #pragma unroll
            for (int cc = 0; cc < 2; ++cc) {
                int c = (nf0 + cc) * 16 + lrow;
                float bhr = p.b_hh[c], bhz = p.b_hh[GHID + c], bhn = p.b_hh[2 * GHID + c];
                #pragma unroll
                for (int r = 0; r < 4; ++r) {
                    int lm = mw * 16 + ((l >> 4) << 2) + r;
                    int m = m0 + lm;
                    const float* tb = p.table + idx_l[lm] * 1536;
                    float rv  = gM[0][cc][r] + gX[0][cc][r] * INV_LO + bhr + tb[c];
                    float zv  = gM[1][cc][r] + gX[1][cc][r] * INV_LO + bhz + tb[GHID + c];
                    float inp = gM[2][cc][r] + gX[2][cc][r] * INV_LO + tb[2 * GHID + c];
                    float hnp = gM[3][cc][r] + gX[3][cc][r] * INV_LO + bhn;
                    float rg = 1.f / (1.f + expf(-rv));
                    float zg = 1.f / (1.f + expf(-zv));
                    float ng = tanhf(inp + rg * hnp);
                    size_t off = (size_t)m * GHID + c;
                    unsigned wprev = __hip_atomic_load((unsigned*)Hp + off,
                                                       __ATOMIC_RELAXED, __HIP_MEMORY_SCOPE_AGENT);
                    float hnv = (1.f - zg) * ng + zg * unpackh(wprev);
                    __hip_atomic_store(Hn + off, packh(hnv),
                                       __ATOMIC_RELAXED, __HIP_MEMORY_SCOPE_AGENT);
                }
            }
        }
    }
}

// ============================================================================
extern "C" void kernel_launch(void* const* d_in, const int* in_sizes, int n_in,
                              void* d_out, int out_size, void* d_ws, size_t ws_size,
                              hipStream_t stream)
{
    const float* z    = (const float*)d_in[1];
    const float* dW   = (const float*)d_in[3];
    const float* db   = (const float*)d_in[4];
    const float* W0   = (const float*)d_in[5];
    const float* g0   = (const float*)d_in[6];
    const float* bb0  = (const float*)d_in[7];
    const float* m0   = (const float*)d_in[8];
    const float* v0   = (const float*)d_in[9];
    const float* al0  = (const float*)d_in[10];
    const float* W1   = (const float*)d_in[11];
    const float* g1   = (const float*)d_in[12];
    const float* bb1  = (const float*)d_in[13];
    const float* m1   = (const float*)d_in[14];
    const float* v1   = (const float*)d_in[15];
    const float* al1  = (const float*)d_in[16];
    const float* W2   = (const float*)d_in[17];
    const float* g2   = (const float*)d_in[18];
    const float* bb2  = (const float*)d_in[19];
    const float* m2   = (const float*)d_in[20];
    const float* v2   = (const float*)d_in[21];
    const float* al2  = (const float*)d_in[22];
    const float* w_px = (const float*)d_in[23];
    const float* b_px = (const float*)d_in[24];
    const float* w_ih = (const float*)d_in[25];
    const float* w_hh = (const float*)d_in[26];
    const float* b_ih = (const float*)d_in[27];
    const float* b_hh = (const float*)d_in[28];
    const float* w_out= (const float*)d_in[29];
    const float* b_out= (const float*)d_in[30];
    float* out = (float*)d_out;

    // ws: hseq(f32) | hA(u32) | hB(u32) | whh H/L | wih H/L | wo H/L | table | bar
    float* ws = (float*)d_ws;
    float* hseq = ws;                                            // 504*2048*42 f32
    unsigned* hA = (unsigned*)(hseq + (size_t)NLFULL * BATCH * 42);
    unsigned* hB = hA + (size_t)BATCH * GHID;
    _Float16* whhH = (_Float16*)(hB + (size_t)BATCH * GHID);     // 3*32*16*512
    _Float16* whhL = whhH + 3 * 32 * 16 * 512;
    _Float16* wihH = whhL + 3 * 32 * 16 * 512;                   // 3*32*2*512
    _Float16* wihL = wihH + 3 * 32 * 2 * 512;
    _Float16* woH  = wihL + 3 * 32 * 2 * 512;                    // 2*16*512
    _Float16* woL  = woH + 2 * 16 * 512;
    float* table = (float*)(woL + 2 * 16 * 512);                 // 22*1536
    int*   bar   = (int*)(table + 22 * 1536);                    // 64

    upsample_kernel<<<dim3(BATCH, 4), 512, 0, stream>>>(
        z, dW, db,
        W0, g0, bb0, m0, v0, al0,
        W1, g1, bb1, m1, v1, al1,
        W2, g2, bb2, m2, v2, al2,
        hseq);

    table_kernel<<<(22 * 1536 + 255) / 256, 256, 0, stream>>>(w_px, b_px, w_ih, b_ih, table);
    pack_whh_kernel<<<(3 * 32 * 16 * 512 + 255) / 256, 256, 0, stream>>>(w_hh, whhH, whhL);
    pack_wih_kernel<<<(3 * 32 * 2 * 512 + 255) / 256, 256, 0, stream>>>(w_ih, wihH, wihL);
    pack_wout_kernel<<<(2 * 16 * 512 + 255) / 256, 256, 0, stream>>>(w_out, woH, woL);
    init_kernel<<<(BATCH * GHID + 255) / 256, 256, 0, stream>>>(hA, bar);

    GruP p;
    p.hA = hA; p.hB = hB;
    p.hseq = hseq; p.table = table;
    p.whhH = whhH; p.whhL = whhL; p.wihH = wihH; p.wihL = wihL;
    p.woH = woH; p.woL = woL;
    p.b_hh = b_hh; p.b_out = b_out;
    p.out = out; p.bar = bar;

    void* args[] = { &p };
    hipError_t e = hipLaunchCooperativeKernel((void*)gru_persistent,
                                              dim3(256), dim3(512), args, 0, stream);
    if (e != hipSuccess) {
        // grid == CU count, 1 block/CU: plain launch is co-resident in practice
        gru_persistent<<<256, 512, 0, stream>>>(p);
    }
}